// Round 3
// baseline (10111.291 us; speedup 1.0000x reference)
//
#include <hip/hip_runtime.h>
#include <stdint.h>

#define BB 512
#define TT 256
#define FF 128
#define HH 256
#define NB 32          // blocks (16 rows each)
#define MR 16
#define EPSL 1e-9f

// ws bf16-element offsets. B-fragment-swizzled: [kt][nt][lane][8],
// elem (kt,nt,lane,j) holds B[k=kt*32+(lane>>4)*8+j][n=nt*16+(lane&15)]
#define E_WDH 0        // kt 4, nt 16  (gamma_h: K=128, N=256)
#define E_WH  32768    // kt 8, nt 8   (x_h:    K=256, N=128)
#define E_WF  65536    // kt 4, nt 8   (z_h:    K=128, N=128, diag zeroed)
#define E_WC  81920    // kt 8, nt 8   (alpha:  K=256, N=128)
#define E_W2  114688   // kt 16, nt 64 (gates:  K=512, N=1024)
#define E_END 638976
#define OFF_MSUM (E_END * 2)            // f32 [256]
#define OFF_PART (OFF_MSUM + 1024)      // f32 [3][TT][NB]

typedef __attribute__((ext_vector_type(8))) short s8v;        // 8 bf16
typedef __attribute__((ext_vector_type(4))) float f4v;        // 4 f32
typedef __attribute__((ext_vector_type(4))) unsigned int u4v; // 16B load payload

__device__ __forceinline__ uint16_t f2bf(float v) {
    uint32_t u = __float_as_uint(v);
    return (uint16_t)((u + 0x7fffu + ((u >> 16) & 1u)) >> 16);  // RNE
}
__device__ __forceinline__ float fexp(float x) { return __expf(x); }
__device__ __forceinline__ float fsigm(float x) { return 1.f / (1.f + __expf(-x)); }
__device__ __forceinline__ float ftanh(float x) {
    float e = __expf(2.f * x);
    return 1.f - 2.f / (e + 1.f);
}
__device__ __forceinline__ uint2 pack4(float a, float b, float c, float d) {
    uint2 r;
    r.x = (uint32_t)f2bf(a) | ((uint32_t)f2bf(b) << 16);
    r.y = (uint32_t)f2bf(c) | ((uint32_t)f2bf(d) << 16);
    return r;
}
// A-swizzled LDS index for element (k, m): lane=(k>>3 &3)*16+m, chunk j=k&7
__device__ __forceinline__ int aidx(int k, int m) {
    return ((k >> 5) << 9) + (((((k >> 3) & 3) << 4) + m) << 3) + (k & 7);
}

// Barrier WITHOUT vmcnt drain: LDS ordering only; weight loads stay in flight.
__device__ __forceinline__ void block_sync() {
    asm volatile("s_waitcnt lgkmcnt(0)\n\ts_barrier" ::: "memory");
}

// ---- register-tier weight pipeline -----------------------------------------
// 20 groups/step (sizes 8,8,8,4, then 16x8 for G4) = 156 fragments.
// WAIT(grp k) -> consume k -> ISSUE(grp k+2).  Counted vmcnt thresholds are
// the number of VMEM ops issued after the group (in-order retirement makes
// any younger pollution safe).  "+v" on the wait ties the consume to the wait.
#define GLD(dst, offe)                                                         \
    asm volatile("global_load_dwordx4 %0, %1, off"                             \
                 : "=v"(dst) : "v"((const void*)(wsu + (offe) + L * 8)))

#define WAITG8(B, N)                                                           \
    asm volatile("s_waitcnt vmcnt(" #N ")"                                     \
                 : "+v"((B)[0]), "+v"((B)[1]), "+v"((B)[2]), "+v"((B)[3]),     \
                   "+v"((B)[4]), "+v"((B)[5]), "+v"((B)[6]), "+v"((B)[7]))

#define WAITG4(B, N)                                                           \
    asm volatile("s_waitcnt vmcnt(" #N ")"                                     \
                 : "+v"((B)[0]), "+v"((B)[1]), "+v"((B)[2]), "+v"((B)[3]))

template <int GRP>
__device__ __forceinline__ void issueGrp(const uint16_t* __restrict__ wsu, int w, int L,
                                         u4v (&B)[8]) {
    #pragma unroll
    for (int e = 0; e < 8; ++e) {
        if constexpr (GRP == 3) { if (e >= 4) break; }
        int off;
        if constexpr (GRP == 0)      off = E_WDH + (((e >> 1) * 16 + 2 * w + (e & 1)) * 512);
        else if constexpr (GRP == 1) off = E_WH + ((e * 8 + w) * 512);
        else if constexpr (GRP == 2) off = (e < 4) ? E_WF + ((e * 8 + w) * 512)
                                                   : E_WC + (((e - 4) * 8 + w) * 512);
        else if constexpr (GRP == 3) off = E_WC + (((4 + e) * 8 + w) * 512);
        else {
            const int u = 8 * (GRP - 4) + e, kt = (u >> 2) & 15, g = u & 3, p = u >> 6;
            off = E_W2 + ((kt * 64 + g * 16 + 2 * w + p) * 512);
        }
        GLD(B[e], off);
    }
}

// G4 step J (0..14): wait grp(4+J), consume (acc interleaved across 4 gates),
// issue grp(6+J) (J<14) or next step's grp0 (J==14).
template <int J>
__device__ __forceinline__ void g4step(const uint16_t* __restrict__ wsu, int w, int L,
                                       u4v (&B)[8], const s8v (&ccf)[4],
                                       const s8v (&agm)[8], const s8v (&hf)[8],
                                       f4v (&accP)[4]) {
    WAITG8(B, 8);
    #pragma unroll
    for (int e = 0; e < 8; ++e) {
        const int u = 8 * J + e, kt = (u >> 2) & 15, g = u & 3;
        s8v bb = __builtin_bit_cast(s8v, B[e]);
        accP[g] = __builtin_amdgcn_mfma_f32_16x16x32_bf16(
            kt < 4 ? ccf[kt] : (kt < 8 ? agm[kt] : hf[kt - 8]), bb, accP[g], 0, 0, 0);
    }
    if constexpr (J < 14) issueGrp<6 + J>(wsu, w, L, B);
    else                  issueGrp<0>(wsu, w, L, B);
}

// ---------------- prep: pack weights into B-fragment bf16 layout ----------------
__global__ void prep_weights(const float* __restrict__ Wdh, const float* __restrict__ Wh,
                             const float* __restrict__ Wf, const float* __restrict__ Wc,
                             const float* __restrict__ Wih, const float* __restrict__ Whh,
                             uint16_t* __restrict__ wsu) {
    const int total = E_END;
    for (int i = blockIdx.x * blockDim.x + threadIdx.x; i < total; i += gridDim.x * blockDim.x) {
        float v;
        if (i < 32768) {                        // WdhB
            int o = i, j = o & 7, lane = (o >> 3) & 63, q = o >> 9;
            int nt = q & 15;  // kt = q>>4
            int k = (q >> 4) * 32 + (lane >> 4) * 8 + j;
            int n = nt * 16 + (lane & 15);
            v = Wdh[n * 128 + k];               // B[k][n] = Wdh[n][k]
        } else if (i < 65536) {                 // WhB
            int o = i - 32768, j = o & 7, lane = (o >> 3) & 63, q = o >> 9;
            int nt = q & 7;
            int k = (q >> 3) * 32 + (lane >> 4) * 8 + j;
            int n = nt * 16 + (lane & 15);
            v = Wh[n * 256 + k];
        } else if (i < 81920) {                 // WfB (diag masked)
            int o = i - 65536, j = o & 7, lane = (o >> 3) & 63, q = o >> 9;
            int nt = q & 7;
            int k = (q >> 3) * 32 + (lane >> 4) * 8 + j;
            int n = nt * 16 + (lane & 15);
            v = (k == n) ? 0.f : Wf[n * 128 + k];
        } else if (i < 114688) {                // WcB
            int o = i - 81920, j = o & 7, lane = (o >> 3) & 63, q = o >> 9;
            int nt = q & 7;
            int k = (q >> 3) * 32 + (lane >> 4) * 8 + j;
            int n = nt * 16 + (lane & 15);
            v = Wc[n * 256 + k];
        } else {                                // W2B
            int o = i - 114688, j = o & 7, lane = (o >> 3) & 63, q = o >> 9;
            int nt = q & 63;
            int k = (q >> 6) * 32 + (lane >> 4) * 8 + j;
            int g = nt * 16 + (lane & 15);
            v = (k < 256) ? Wih[g * 256 + k] : Whh[g * 256 + (k - 256)];
        }
        wsu[i] = f2bf(v);
    }
}

// ---------------- msum[t] ----------------
__global__ void msum_kernel(const float* __restrict__ mask, float* __restrict__ msum) {
    int t = blockIdx.x;
    float s = 0.f;
    for (int i = threadIdx.x; i < BB * FF; i += 256) {
        int b = i >> 7, f = i & 127;
        s += mask[((long)b * TT + t) * FF + f];
    }
    __shared__ float red[4];
    for (int off = 32; off; off >>= 1) s += __shfl_down(s, off);
    if ((threadIdx.x & 63) == 0) red[threadIdx.x >> 6] = s;
    __syncthreads();
    if (threadIdx.x == 0) msum[t] = red[0] + red[1] + red[2] + red[3];
}

// ---------------- main: 32 blocks x 512 threads (8 waves), 16 rows/block ----------------
// Wave w owns h-columns [32w,32w+32). Weights stream L2 -> VGPR via asm
// global_load groups with counted vmcnt waits. LSTM h/c state in registers.
__launch_bounds__(512, 2)
__global__ void rits_main(const float* __restrict__ values, const float* __restrict__ mask,
                          const float* __restrict__ deltas,
                          const float* __restrict__ bdh, const float* __restrict__ Wdx,
                          const float* __restrict__ bdx, const float* __restrict__ bh,
                          const float* __restrict__ bf_, const float* __restrict__ bc_,
                          const float* __restrict__ bih, const float* __restrict__ bhh,
                          const uint16_t* __restrict__ wsu,
                          float* __restrict__ part, float* __restrict__ out_imp) {
    __shared__ __align__(16) uint16_t dA[4 * 512];     // d,  A-layout, K=128
    __shared__ __align__(16) uint16_t gxmA[8 * 512];   // [gx|m], K=256
    __shared__ __align__(16) uint16_t hA[8 * 512];     // decayed h, K=256
    __shared__ __align__(16) uint16_t xcA[4 * 512];    // x_c, K=128
    __shared__ __align__(16) uint16_t ccA[4 * 512];    // c_c, K=128
    __shared__ __align__(16) float x32[16 * 132];
    __shared__ __align__(16) float m32[16 * 132];
    __shared__ float wred[3][8];

    const int tid = threadIdx.x;
    const int blk = blockIdx.x;
    const int r0 = blk * MR;
    const int w = tid >> 6;        // wave 0..7
    const int L = tid & 63;        // lane
    const int col = L & 15;
    const int q = L >> 4;

    // ---- hoisted per-thread constants ----
    const int rowi = tid >> 5;          // staging row
    const int f4 = (tid & 31) * 4;      // staging f base
    float cwdx[4], cbdx[4];
    #pragma unroll
    for (int e = 0; e < 4; ++e) {
        cwdx[e] = Wdx[(f4 + e) * FF + (f4 + e)];
        cbdx[e] = bdx[f4 + e];
    }
    const float bdh0 = bdh[32 * w + col];
    const float bdh1 = bdh[32 * w + 16 + col];
    const int fw = 16 * w + col;        // this wave's f column (N=128 stages)
    const float c_bh = bh[fw], c_bf = bf_[fw], c_bc = bc_[fw];
    float gbv[8];                       // gate bias, idx s=p*4+g for tile g*16+2w+p
    #pragma unroll
    for (int s = 0; s < 8; ++s) {
        int p = s >> 2, g = s & 3;
        int gi = (g * 16 + 2 * w + p) * 16 + col;
        gbv[s] = bih[gi] + bhh[gi];
    }

    // persistent LSTM state: idx p*4+r -> (row q*4+r, col 32w+16p+col)
    float cst[8], hv[8];
    #pragma unroll
    for (int e = 0; e < 8; ++e) { cst[e] = 0.f; hv[e] = 0.f; }

    // ---- prologue: load + stage t=0 inputs (plain loads; no asm loads yet) ----
    {
        long base = ((long)(r0 + rowi) * TT + 0) * FF + f4;
        float4 xv = *(const float4*)(values + base);
        float4 mv = *(const float4*)(mask + base);
        float4 dv = *(const float4*)(deltas + base);
        *(float4*)(x32 + rowi * 132 + f4) = xv;
        *(float4*)(m32 + rowi * 132 + f4) = mv;
        float g0 = fexp(-fmaxf(dv.x * cwdx[0] + cbdx[0], 0.f));
        float g1 = fexp(-fmaxf(dv.y * cwdx[1] + cbdx[1], 0.f));
        float g2 = fexp(-fmaxf(dv.z * cwdx[2] + cbdx[2], 0.f));
        float g3 = fexp(-fmaxf(dv.w * cwdx[3] + cbdx[3], 0.f));
        *(uint2*)(dA + aidx(f4, rowi)) = pack4(dv.x, dv.y, dv.z, dv.w);
        *(uint2*)(gxmA + aidx(f4, rowi)) = pack4(g0, g1, g2, g3);
        *(uint2*)(gxmA + aidx(128 + f4, rowi)) = pack4(mv.x, mv.y, mv.z, mv.w);
    }
    u4v bufA[8], bufB[8];
    f4v xvr, mvr, dvr;                  // next-step inputs (asm-loaded in G3)
    issueGrp<0>(wsu, w, L, bufA);       // grp0 -> G1
    issueGrp<1>(wsu, w, L, bufB);       // grp1 -> G2
    block_sync();                       // S1 (t=0)

    #pragma unroll 1
    for (int t = 0; t < TT; ++t) {
        // ================= G1: gamma_h GEMM + decay h (h in registers) =================
        {
            s8v ad[4];
            #pragma unroll
            for (int kt = 0; kt < 4; ++kt) ad[kt] = *(const s8v*)(dA + kt * 512 + L * 8);
            f4v ac0 = {0.f, 0.f, 0.f, 0.f}, ac1 = ac0;
            WAITG8(bufA, 8);                                   // grp0 (grp1 after it)
            #pragma unroll
            for (int e = 0; e < 8; ++e) {
                s8v bb = __builtin_bit_cast(s8v, bufA[e]);
                if (e & 1) ac1 = __builtin_amdgcn_mfma_f32_16x16x32_bf16(ad[e >> 1], bb, ac1, 0, 0, 0);
                else       ac0 = __builtin_amdgcn_mfma_f32_16x16x32_bf16(ad[e >> 1], bb, ac0, 0, 0, 0);
            }
            issueGrp<2>(wsu, w, L, bufA);                      // grp2 -> G3
            #pragma unroll
            for (int r = 0; r < 4; ++r) {
                int m = q * 4 + r;
                int n0 = 32 * w + col;
                float hd0 = hv[r] * fexp(-fmaxf(ac0[r] + bdh0, 0.f));
                hA[aidx(n0, m)] = f2bf(hd0);
                int n1 = n0 + 16;
                float hd1 = hv[4 + r] * fexp(-fmaxf(ac1[r] + bdh1, 0.f));
                hA[aidx(n1, m)] = f2bf(hd1);
            }
        }
        block_sync();  // S2

        // ================= G2: x_h GEMM, loss1, x_c =================
        float xh[4], xr[4], mr[4], acc1 = 0.f;
        {
            s8v ah[8];
            #pragma unroll
            for (int kt = 0; kt < 8; ++kt) ah[kt] = *(const s8v*)(hA + kt * 512 + L * 8);
            f4v a = {0.f, 0.f, 0.f, 0.f};
            WAITG8(bufB, 8);                                   // grp1 (grp2 after it)
            #pragma unroll
            for (int e = 0; e < 8; ++e) {
                s8v bb = __builtin_bit_cast(s8v, bufB[e]);
                a = __builtin_amdgcn_mfma_f32_16x16x32_bf16(ah[e], bb, a, 0, 0, 0);
            }
            issueGrp<3>(wsu, w, L, bufB);                      // grp3 (4 loads) -> G3
            #pragma unroll
            for (int r = 0; r < 4; ++r) {
                int m = q * 4 + r;
                xh[r] = a[r] + c_bh;
                xr[r] = x32[m * 132 + fw];
                mr[r] = m32[m * 132 + fw];
                acc1 += fabsf(xh[r] - xr[r]) * mr[r];
                float xc = mr[r] * xr[r] + (1.f - mr[r]) * xh[r];
                xcA[aidx(fw, m)] = f2bf(xc);
            }
        }
        block_sync();  // S3

        // ================= G3: z_h + alpha GEMMs, c_h, losses, c_c =================
        s8v agm[8];                               // kept live into G4 (A kt4-7 = m)
        {
            // next-step input loads (asm; pollution-safe: younger than grp2)
            const int tn = (t + 1 < TT) ? t + 1 : t;
            {
                const float* xb = values + (((long)(r0 + rowi) * TT + tn) * FF + f4);
                const float* mb = mask   + (((long)(r0 + rowi) * TT + tn) * FF + f4);
                const float* db = deltas + (((long)(r0 + rowi) * TT + tn) * FF + f4);
                asm volatile("global_load_dwordx4 %0, %1, off" : "=v"(xvr) : "v"(xb));
                asm volatile("global_load_dwordx4 %0, %1, off" : "=v"(mvr) : "v"(mb));
                asm volatile("global_load_dwordx4 %0, %1, off" : "=v"(dvr) : "v"(db));
            }
            s8v axc[4];
            #pragma unroll
            for (int kt = 0; kt < 4; ++kt) axc[kt] = *(const s8v*)(xcA + kt * 512 + L * 8);
            #pragma unroll
            for (int kt = 0; kt < 8; ++kt) agm[kt] = *(const s8v*)(gxmA + kt * 512 + L * 8);
            f4v az = {0.f, 0.f, 0.f, 0.f}, aa = az;
            WAITG8(bufA, 7);              // grp2: issued-after = grp3(4)+inputs(3)
            #pragma unroll
            for (int e = 0; e < 4; ++e) {
                s8v bz = __builtin_bit_cast(s8v, bufA[e]);
                s8v bc = __builtin_bit_cast(s8v, bufA[e + 4]);
                az = __builtin_amdgcn_mfma_f32_16x16x32_bf16(axc[e], bz, az, 0, 0, 0);
                aa = __builtin_amdgcn_mfma_f32_16x16x32_bf16(agm[e], bc, aa, 0, 0, 0);
            }
            issueGrp<4>(wsu, w, L, bufA);                      // grp4 -> G4 j=0
            WAITG4(bufB, 8);              // grp3: issued-after = inputs(3)+grp4(8)
            #pragma unroll
            for (int e = 0; e < 4; ++e) {
                s8v bc = __builtin_bit_cast(s8v, bufB[e]);
                aa = __builtin_amdgcn_mfma_f32_16x16x32_bf16(agm[4 + e], bc, aa, 0, 0, 0);
            }
            issueGrp<5>(wsu, w, L, bufB);                      // grp5 -> G4 j=1
            float acc2 = 0.f, acc3 = 0.f;
            #pragma unroll
            for (int r = 0; r < 4; ++r) {
                int m = q * 4 + r;
                float zh = az[r] + c_bf;
                float al = aa[r] + c_bc;
                float ch = al * zh + (1.f - al) * xh[r];
                acc2 += fabsf(zh - xr[r]) * mr[r];
                acc3 += fabsf(ch - xr[r]) * mr[r];
                float cc = mr[r] * xr[r] + (1.f - mr[r]) * ch;
                out_imp[((long)(r0 + m) * TT + t) * FF + fw] = cc;
                ccA[aidx(fw, m)] = f2bf(cc);
            }
            float a1 = acc1, a2 = acc2, a3 = acc3;
            for (int off = 32; off; off >>= 1) {
                a1 += __shfl_down(a1, off);
                a2 += __shfl_down(a2, off);
                a3 += __shfl_down(a3, off);
            }
            if (L == 0) { wred[0][w] = a1; wred[1][w] = a2; wred[2][w] = a3; }
        }
        block_sync();  // S4

        if (tid < 3) {
            float s = 0.f;
            #pragma unroll
            for (int e = 0; e < 8; ++e) s += wred[tid][e];
            part[((long)tid * TT + t) * NB + blk] = s;
        }

        // ================= G4: gates GEMM (K=512), reg-pipelined + LSTM + stage t+1 =====
        {
            s8v ccf[4], hf[8];                    // A kt0-3 (c_c), kt8-15 (h)
            #pragma unroll
            for (int kt = 0; kt < 4; ++kt) ccf[kt] = *(const s8v*)(ccA + kt * 512 + L * 8);
            #pragma unroll
            for (int kt = 0; kt < 8; ++kt) hf[kt] = *(const s8v*)(hA + kt * 512 + L * 8);
            f4v accP[4];
            #pragma unroll
            for (int g = 0; g < 4; ++g) accP[g] = (f4v){0.f, 0.f, 0.f, 0.f};

            g4step<0>(wsu, w, L, bufA, ccf, agm, hf, accP);
            g4step<1>(wsu, w, L, bufB, ccf, agm, hf, accP);
            g4step<2>(wsu, w, L, bufA, ccf, agm, hf, accP);
            g4step<3>(wsu, w, L, bufB, ccf, agm, hf, accP);
            g4step<4>(wsu, w, L, bufA, ccf, agm, hf, accP);
            g4step<5>(wsu, w, L, bufB, ccf, agm, hf, accP);
            g4step<6>(wsu, w, L, bufA, ccf, agm, hf, accP);
            g4step<7>(wsu, w, L, bufB, ccf, agm, hf, accP);
            // LSTM pointwise p=0 (cols 32w+col)
            #pragma unroll
            for (int r = 0; r < 4; ++r) {
                float gi = accP[0][r] + gbv[0];
                float gf = accP[1][r] + gbv[1];
                float gg = accP[2][r] + gbv[2];
                float go = accP[3][r] + gbv[3];
                float ct = fsigm(gf) * cst[r] + fsigm(gi) * ftanh(gg);
                cst[r] = ct;
                hv[r] = fsigm(go) * ftanh(ct);
            }
            #pragma unroll
            for (int g = 0; g < 4; ++g) accP[g] = (f4v){0.f, 0.f, 0.f, 0.f};

            g4step<8>(wsu, w, L, bufA, ccf, agm, hf, accP);
            g4step<9>(wsu, w, L, bufB, ccf, agm, hf, accP);
            g4step<10>(wsu, w, L, bufA, ccf, agm, hf, accP);
            g4step<11>(wsu, w, L, bufB, ccf, agm, hf, accP);
            g4step<12>(wsu, w, L, bufA, ccf, agm, hf, accP);
            g4step<13>(wsu, w, L, bufB, ccf, agm, hf, accP);
            g4step<14>(wsu, w, L, bufA, ccf, agm, hf, accP);  // issues next grp0
            // j=15: wait also covers the input loads (older than grp19)
            asm volatile("s_waitcnt vmcnt(8)"
                : "+v"(bufB[0]), "+v"(bufB[1]), "+v"(bufB[2]), "+v"(bufB[3]),
                  "+v"(bufB[4]), "+v"(bufB[5]), "+v"(bufB[6]), "+v"(bufB[7]),
                  "+v"(xvr), "+v"(mvr), "+v"(dvr));
            #pragma unroll
            for (int e = 0; e < 8; ++e) {
                const int u = 120 + e, kt = (u >> 2) & 15, g = u & 3;
                s8v bb = __builtin_bit_cast(s8v, bufB[e]);
                accP[g] = __builtin_amdgcn_mfma_f32_16x16x32_bf16(
                    kt < 8 ? agm[kt] : hf[kt - 8], bb, accP[g], 0, 0, 0);
            }
            issueGrp<1>(wsu, w, L, bufB);                      // next step's grp1
            // LSTM pointwise p=1 (cols 32w+16+col)
            #pragma unroll
            for (int r = 0; r < 4; ++r) {
                float gi = accP[0][r] + gbv[4];
                float gf = accP[1][r] + gbv[5];
                float gg = accP[2][r] + gbv[6];
                float go = accP[3][r] + gbv[7];
                float ct = fsigm(gf) * cst[4 + r] + fsigm(gi) * ftanh(gg);
                cst[4 + r] = ct;
                hv[4 + r] = fsigm(go) * ftanh(ct);
            }
            // stage inputs for t+1 (x32/m32/dA/gxmA last read before S4)
            *(f4v*)(x32 + rowi * 132 + f4) = xvr;
            *(f4v*)(m32 + rowi * 132 + f4) = mvr;
            float g0 = fexp(-fmaxf(dvr[0] * cwdx[0] + cbdx[0], 0.f));
            float g1 = fexp(-fmaxf(dvr[1] * cwdx[1] + cbdx[1], 0.f));
            float g2 = fexp(-fmaxf(dvr[2] * cwdx[2] + cbdx[2], 0.f));
            float g3 = fexp(-fmaxf(dvr[3] * cwdx[3] + cbdx[3], 0.f));
            *(uint2*)(dA + aidx(f4, rowi)) = pack4(dvr[0], dvr[1], dvr[2], dvr[3]);
            *(uint2*)(gxmA + aidx(f4, rowi)) = pack4(g0, g1, g2, g3);
            *(uint2*)(gxmA + aidx(128 + f4, rowi)) = pack4(mvr[0], mvr[1], mvr[2], mvr[3]);
        }
        block_sync();  // S5 == next step's S1
    }
}

// ---------------- finisher ----------------
__global__ void finisher(const float* __restrict__ part, const float* __restrict__ msum,
                         float* __restrict__ out2) {
    int t = threadIdx.x;
    float s1 = 0.f, s2 = 0.f, s3 = 0.f;
    const float* p1 = part + ((long)0 * TT + t) * NB;
    const float* p2 = part + ((long)1 * TT + t) * NB;
    const float* p3 = part + ((long)2 * TT + t) * NB;
    for (int b = 0; b < NB; ++b) { s1 += p1[b]; s2 += p2[b]; s3 += p3[b]; }
    float den = msum[t] + EPSL;
    float l12 = (s1 + s2) / den;
    float l3 = s3 / den;
    float xl = l12 + (float)(TT - t) * l3;
    float ml = l3;
    __shared__ float r1[4], r2[4];
    for (int off = 32; off; off >>= 1) {
        xl += __shfl_down(xl, off);
        ml += __shfl_down(ml, off);
    }
    if ((t & 63) == 0) { r1[t >> 6] = xl; r2[t >> 6] = ml; }
    __syncthreads();
    if (t == 0) {
        float X = r1[0] + r1[1] + r1[2] + r1[3];
        float M = r2[0] + r2[1] + r2[2] + r2[3];
        out2[0] = X / (float)(TT * 3);
        out2[1] = M / (float)TT;
    }
}

extern "C" void kernel_launch(void* const* d_in, const int* in_sizes, int n_in,
                              void* d_out, int out_size, void* d_ws, size_t ws_size,
                              hipStream_t stream) {
    const float* values = (const float*)d_in[0];
    const float* mask   = (const float*)d_in[1];
    const float* deltas = (const float*)d_in[2];
    const float* Wdh = (const float*)d_in[3];
    const float* bdh = (const float*)d_in[4];
    const float* Wdx = (const float*)d_in[5];
    const float* bdx = (const float*)d_in[6];
    const float* Wh  = (const float*)d_in[7];
    const float* bh  = (const float*)d_in[8];
    const float* Wf  = (const float*)d_in[9];
    const float* bf_ = (const float*)d_in[10];
    const float* Wc  = (const float*)d_in[11];
    const float* bc_ = (const float*)d_in[12];
    const float* Wih = (const float*)d_in[13];
    const float* Whh = (const float*)d_in[14];
    const float* bih = (const float*)d_in[15];
    const float* bhh = (const float*)d_in[16];

    float* out = (float*)d_out;
    uint16_t* wsu = (uint16_t*)d_ws;
    float* msum = (float*)((char*)d_ws + OFF_MSUM);
    float* part = (float*)((char*)d_ws + OFF_PART);

    prep_weights<<<2496, 256, 0, stream>>>(Wdh, Wh, Wf, Wc, Wih, Whh, wsu);
    msum_kernel<<<TT, 256, 0, stream>>>(mask, msum);
    rits_main<<<NB, 512, 0, stream>>>(values, mask, deltas, bdh, Wdx, bdx,
                                      bh, bf_, bc_, bih, bhh, wsu, part, out);
    finisher<<<1, 256, 0, stream>>>(part, msum, out + (long)BB * TT * FF);
}

// Round 5
// 4831.277 us; speedup vs baseline: 2.0929x; 2.0929x over previous
//
#include <hip/hip_runtime.h>
#include <stdint.h>

#define BB 512
#define TT 256
#define FF 128
#define HH 256
#define NB 32          // blocks (16 rows each)
#define MR 16
#define EPSL 1e-9f

#define NWV 16                          // waves per block
#define FRW 80                          // fragments per wave-stream (uniform, incl pad)
#define E_STREAM (NWV * FRW * 512)      // 655360 bf16 elements
#define OFF_MSUM (E_STREAM * 2)         // byte offset of msum [256] f32
#define OFF_PART (OFF_MSUM + 1024)      // byte offset of part [3][TT] f32 (atomic-accumulated)

typedef __attribute__((ext_vector_type(8))) short s8v;        // 8 bf16
typedef __attribute__((ext_vector_type(4))) float f4v;        // 4 f32
typedef __attribute__((ext_vector_type(2))) float f2v;        // 2 f32
typedef __attribute__((ext_vector_type(4))) unsigned int u4v; // 16B payload

__device__ __forceinline__ uint16_t f2bf(float v) {
    uint32_t u = __float_as_uint(v);
    return (uint16_t)((u + 0x7fffu + ((u >> 16) & 1u)) >> 16);  // RNE
}
__device__ __forceinline__ float fexp(float x) { return __expf(x); }
__device__ __forceinline__ float fsigm(float x) { return 1.f / (1.f + __expf(-x)); }
__device__ __forceinline__ float ftanh(float x) {
    float e = __expf(2.f * x);
    return 1.f - 2.f / (e + 1.f);
}
__device__ __forceinline__ uint32_t pack2(float a, float b) {
    return (uint32_t)f2bf(a) | ((uint32_t)f2bf(b) << 16);
}
// A-swizzled LDS index for element (k, m): lane=(k>>3 &3)*16+m, chunk j=k&7
__device__ __forceinline__ int aidx(int k, int m) {
    return ((k >> 5) << 9) + (((((k >> 3) & 3) << 4) + m) << 3) + (k & 7);
}

// Barrier WITHOUT vmcnt drain: LDS ordering only; weight loads stay in flight.
__device__ __forceinline__ void block_sync() {
    asm volatile("s_waitcnt lgkmcnt(0)\n\ts_barrier" ::: "memory");
}

// Issue one 4-fragment group (4 KB) from the wave's linear stream.
// Single asm block -> contiguous issue order (counts stay exact).
// "=&v" EARLY-CLOBBER is mandatory: outputs must not alias the address pair,
// or loads 2-4 read a corrupted pointer (round-4 fault).
#define ISSUE4(B, ptr)                                                         \
    asm volatile("global_load_dwordx4 %0, %4, off\n\t"                         \
                 "global_load_dwordx4 %1, %4, off offset:1024\n\t"             \
                 "global_load_dwordx4 %2, %4, off offset:2048\n\t"             \
                 "global_load_dwordx4 %3, %4, off offset:3072"                 \
                 : "=&v"((B)[0]), "=&v"((B)[1]), "=&v"((B)[2]), "=&v"((B)[3])  \
                 : "v"((const void*)(ptr)))

// Counted wait; N = number of younger asm weight-loads (plain stores/atomics
// issued in between only make the wait stricter -> always safe).
#define WAIT4(B, N)                                                            \
    asm volatile("s_waitcnt vmcnt(" #N ")"                                     \
                 : "+v"((B)[0]), "+v"((B)[1]), "+v"((B)[2]), "+v"((B)[3]))

// ---------------- prep: pack weights into per-wave linear streams ----------------
// Wave v stream (80 frags x 1KB): [0..3]=gamma_h tile v (Wdh kt0-3)
//  v<8:  [4..11]=Wh kt0-7 (tile v) | [12..15]=Wf kt0-3 (diag 0) | [16..79]=G4
//  v>=8: [4..11]=Wc kt0-7 (tile v-8) | [12..15]=pad | [16..79]=G4
// G4 order: u=fi-16: kq=u>>4, g=(u>>2)&3, e=u&3 -> kt=kq*4+e, gate-col tile g*16+v.
__global__ void prep_weights(const float* __restrict__ Wdh, const float* __restrict__ Wh,
                             const float* __restrict__ Wf, const float* __restrict__ Wc,
                             const float* __restrict__ Wih, const float* __restrict__ Whh,
                             uint16_t* __restrict__ wsu) {
    for (int i = blockIdx.x * blockDim.x + threadIdx.x; i < E_STREAM;
         i += gridDim.x * blockDim.x) {
        int j = i & 7, lane = (i >> 3) & 63, fg = i >> 9;
        int v = fg / FRW, fi = fg % FRW;
        int lo = lane & 15, hi = lane >> 4;
        float val = 0.f;
        if (fi < 4) {
            int k = fi * 32 + hi * 8 + j, n = v * 16 + lo;
            val = Wdh[n * 128 + k];
        } else if (fi < 12) {
            int k = (fi - 4) * 32 + hi * 8 + j;
            if (v < 8) val = Wh[(v * 16 + lo) * 256 + k];
            else       val = Wc[((v - 8) * 16 + lo) * 256 + k];
        } else if (fi < 16) {
            if (v < 8) {
                int k = (fi - 12) * 32 + hi * 8 + j, n = v * 16 + lo;
                val = (k == n) ? 0.f : Wf[n * 128 + k];
            }                                   // v>=8: pad (never consumed)
        } else {
            int u = fi - 16, kq = u >> 4, g = (u >> 2) & 3, e = u & 3;
            int k = (kq * 4 + e) * 32 + hi * 8 + j;
            int gc = (g * 16 + v) * 16 + lo;
            val = (k < 256) ? Wih[gc * 256 + k] : Whh[gc * 256 + (k - 256)];
        }
        wsu[i] = f2bf(val);
    }
}

// ---------------- msum[t] + zero the loss accumulators ----------------
__global__ void msum_kernel(const float* __restrict__ mask, float* __restrict__ msum,
                            float* __restrict__ part) {
    int t = blockIdx.x;
    if (threadIdx.x < 3) part[threadIdx.x * TT + t] = 0.f;
    float s = 0.f;
    for (int i = threadIdx.x; i < BB * FF; i += 256) {
        int b = i >> 7, f = i & 127;
        s += mask[((long)b * TT + t) * FF + f];
    }
    __shared__ float red[4];
    for (int off = 32; off; off >>= 1) s += __shfl_down(s, off);
    if ((threadIdx.x & 63) == 0) red[threadIdx.x >> 6] = s;
    __syncthreads();
    if (threadIdx.x == 0) msum[t] = red[0] + red[1] + red[2] + red[3];
}

// ---------------- main: 32 blocks x 1024 threads (16 waves, 4/SIMD) ----------------
// Wave v owns h-columns [16v,16v+16). Weights stream linearly L2->VGPR in
// 4-frag groups, depth-2 double buffer, counted vmcnt. LSTM h/c in registers.
__launch_bounds__(1024, 4)
__global__ void rits_main(const float* __restrict__ values, const float* __restrict__ mask,
                          const float* __restrict__ deltas,
                          const float* __restrict__ bdh, const float* __restrict__ Wdx,
                          const float* __restrict__ bdx, const float* __restrict__ bh,
                          const float* __restrict__ bf_, const float* __restrict__ bc_,
                          const float* __restrict__ bih, const float* __restrict__ bhh,
                          const uint16_t* __restrict__ wsu,
                          float* __restrict__ part, float* __restrict__ out_imp) {
    __shared__ __align__(16) uint16_t dA[4 * 512];     // d,  A-layout, K=128
    __shared__ __align__(16) uint16_t gxmA[8 * 512];   // [gx|m], K=256
    __shared__ __align__(16) uint16_t hA[8 * 512];     // decayed h, K=256
    __shared__ __align__(16) uint16_t xcA[4 * 512];    // x_c, K=128
    __shared__ __align__(16) uint16_t ccA[4 * 512];    // c_c, K=128
    __shared__ __align__(16) float x32[16 * 132];
    __shared__ __align__(16) float m32[16 * 132];
    __shared__ __align__(16) float al32[16 * 132];     // alpha (bias included)
    __shared__ float wred[3][8];

    const int tid = threadIdx.x;
    const int blk = blockIdx.x;
    const int r0 = blk * MR;
    const int v = tid >> 6;        // wave 0..15
    const int L = tid & 63;
    const int col = L & 15;
    const int q = L >> 4;
    const int vl = v & 7;

    // ---- per-thread constants ----
    const int f2 = L * 2;               // staging: row v, feats f2,f2+1
    const float cwdx0 = Wdx[f2 * FF + f2], cwdx1 = Wdx[(f2 + 1) * FF + f2 + 1];
    const float cbdx0 = bdx[f2], cbdx1 = bdx[f2 + 1];
    const float c_bdh = bdh[v * 16 + col];
    const int fw = vl * 16 + col;
    const float c_bh = bh[fw], c_bf = bf_[fw], c_bc = bc_[fw];
    float gbv[4];
    #pragma unroll
    for (int g = 0; g < 4; ++g) {
        int gi = (g * 16 + v) * 16 + col;
        gbv[g] = bih[gi] + bhh[gi];
    }
    float cst[4] = {0.f, 0.f, 0.f, 0.f}, hv[4] = {0.f, 0.f, 0.f, 0.f};

    const uint16_t* wb = wsu + v * (FRW * 512) + L * 8;   // wave stream base

    // ---- prologue: t=0 inputs (plain loads), stage x/m/d ----
    const long rowbase = ((long)(r0 + v) * TT) * FF + f2;
    f2v xvr = *(const f2v*)(values + rowbase);
    f2v mvr = *(const f2v*)(mask + rowbase);
    f2v dvr = *(const f2v*)(deltas + rowbase);
    *(f2v*)(x32 + v * 132 + f2) = xvr;
    *(f2v*)(m32 + v * 132 + f2) = mvr;
    *(uint32_t*)(dA + aidx(f2, v)) = pack2(dvr[0], dvr[1]);
    const float* xp = values + rowbase + FF;   // t+1 pointers
    const float* mp = mask + rowbase + FF;
    const float* dp = deltas + rowbase + FF;

    u4v bufA[4], bufB[4];
    ISSUE4(bufA, wb);              // g0
    ISSUE4(bufB, wb + 2048);       // g1
    block_sync();                  // S1

    #pragma unroll 1
    for (int t = 0; t < TT; ++t) {
        // ===== P1: stage gxm[t] (from regs) + gamma_h GEMM + decay h =====
        {
            float g0 = fexp(-fmaxf(dvr[0] * cwdx0 + cbdx0, 0.f));
            float g1 = fexp(-fmaxf(dvr[1] * cwdx1 + cbdx1, 0.f));
            *(uint32_t*)(gxmA + aidx(f2, v)) = pack2(g0, g1);
            *(uint32_t*)(gxmA + aidx(128 + f2, v)) = pack2(mvr[0], mvr[1]);
            s8v ad[4];
            #pragma unroll
            for (int kt = 0; kt < 4; ++kt) ad[kt] = *(const s8v*)(dA + kt * 512 + L * 8);
            f4v acc = {0.f, 0.f, 0.f, 0.f};
            WAIT4(bufA, 4);        // g0 (younger: g1)
            #pragma unroll
            for (int e = 0; e < 4; ++e)
                acc = __builtin_amdgcn_mfma_f32_16x16x32_bf16(
                    ad[e], __builtin_bit_cast(s8v, bufA[e]), acc, 0, 0, 0);
            ISSUE4(bufA, wb + 2 * 2048);   // g2
            #pragma unroll
            for (int r = 0; r < 4; ++r) {
                int m = q * 4 + r;
                float hd = hv[r] * fexp(-fmaxf(acc[r] + c_bdh, 0.f));
                hA[aidx(v * 16 + col, m)] = f2bf(hd);
            }
        }
        block_sync();  // S2

        // ===== P2: w0-7 x_h (A=hA) | w8-15 alpha (A=gxmA) =====
        float xh[4], xr[4], mr[4], acc1 = 0.f;
        {
            const uint16_t* Aarr = (v < 8) ? hA : gxmA;
            s8v a0[4];
            #pragma unroll
            for (int kk = 0; kk < 4; ++kk) a0[kk] = *(const s8v*)(Aarr + kk * 512 + L * 8);
            f4v acc = {0.f, 0.f, 0.f, 0.f};
            WAIT4(bufB, 4);        // g1 (younger: g2)
            #pragma unroll
            for (int e = 0; e < 4; ++e)
                acc = __builtin_amdgcn_mfma_f32_16x16x32_bf16(
                    a0[e], __builtin_bit_cast(s8v, bufB[e]), acc, 0, 0, 0);
            ISSUE4(bufB, wb + 3 * 2048);   // g3
            s8v a1[4];
            #pragma unroll
            for (int kk = 0; kk < 4; ++kk) a1[kk] = *(const s8v*)(Aarr + (4 + kk) * 512 + L * 8);
            WAIT4(bufA, 4);        // g2 (younger: g3)
            #pragma unroll
            for (int e = 0; e < 4; ++e)
                acc = __builtin_amdgcn_mfma_f32_16x16x32_bf16(
                    a1[e], __builtin_bit_cast(s8v, bufA[e]), acc, 0, 0, 0);
            ISSUE4(bufA, wb + 4 * 2048);   // g4
            if (v < 8) {
                #pragma unroll
                for (int r = 0; r < 4; ++r) {
                    int m = q * 4 + r;
                    xh[r] = acc[r] + c_bh;
                    xr[r] = x32[m * 132 + fw];
                    mr[r] = m32[m * 132 + fw];
                    acc1 += fabsf(xh[r] - xr[r]) * mr[r];
                    float xc = mr[r] * xr[r] + (1.f - mr[r]) * xh[r];
                    xcA[aidx(fw, m)] = f2bf(xc);
                }
            } else {
                #pragma unroll
                for (int r = 0; r < 4; ++r)
                    al32[(q * 4 + r) * 132 + fw] = acc[r] + c_bc;
            }
        }
        block_sync();  // S3

        // ===== P3: input prefetch (asm) + w0-7 z_h/combine | w8-15 pad retire =====
        {
            asm volatile("global_load_dwordx2 %0, %1, off" : "=&v"(xvr) : "v"(xp));
            asm volatile("global_load_dwordx2 %0, %1, off" : "=&v"(mvr) : "v"(mp));
            asm volatile("global_load_dwordx2 %0, %1, off" : "=&v"(dvr) : "v"(dp));
            if (t < TT - 2) { xp += FF; mp += FF; dp += FF; }
            if (v < 8) {
                s8v ax[4];
                #pragma unroll
                for (int kk = 0; kk < 4; ++kk) ax[kk] = *(const s8v*)(xcA + kk * 512 + L * 8);
                f4v az = {0.f, 0.f, 0.f, 0.f};
                WAIT4(bufB, 7);    // g3 (younger: g4 + 3 inputs)
                #pragma unroll
                for (int e = 0; e < 4; ++e)
                    az = __builtin_amdgcn_mfma_f32_16x16x32_bf16(
                        ax[e], __builtin_bit_cast(s8v, bufB[e]), az, 0, 0, 0);
                ISSUE4(bufB, wb + 5 * 2048);   // g5
                float acc2 = 0.f, acc3 = 0.f;
                #pragma unroll
                for (int r = 0; r < 4; ++r) {
                    int m = q * 4 + r;
                    float zh = az[r] + c_bf;
                    float al = al32[m * 132 + fw];
                    float ch = al * zh + (1.f - al) * xh[r];
                    acc2 += fabsf(zh - xr[r]) * mr[r];
                    acc3 += fabsf(ch - xr[r]) * mr[r];
                    float cc = mr[r] * xr[r] + (1.f - mr[r]) * ch;
                    out_imp[((long)(r0 + m) * TT + t) * FF + fw] = cc;
                    ccA[aidx(fw, m)] = f2bf(cc);
                }
                float a1 = acc1, a2 = acc2, a3 = acc3;
                for (int off = 32; off; off >>= 1) {
                    a1 += __shfl_down(a1, off);
                    a2 += __shfl_down(a2, off);
                    a3 += __shfl_down(a3, off);
                }
                if (L == 0) { wred[0][v] = a1; wred[1][v] = a2; wred[2][v] = a3; }
            } else {
                WAIT4(bufB, 7);    // pad group g3: retire only
                ISSUE4(bufB, wb + 5 * 2048);   // g5
            }
        }
        block_sync();  // S4

        if (tid < 3) {
            float s = 0.f;
            #pragma unroll
            for (int e = 0; e < 8; ++e) s += wred[tid][e];
            atomicAdd(part + tid * TT + t, s);
        }

        // ===== P4: gates GEMM (4 tiles, K=512) + LSTM + stage t+1 =====
        {
            f4v accP[4];
            #pragma unroll
            for (int g = 0; g < 4; ++g) accP[g] = (f4v){0.f, 0.f, 0.f, 0.f};
            #pragma unroll
            for (int kq = 0; kq < 4; ++kq) {
                __builtin_amdgcn_sched_barrier(0);
                const uint16_t* asrc = (kq == 0) ? ccA
                                     : (kq == 1) ? (gxmA + 4 * 512)
                                                 : (hA + (kq - 2) * 4 * 512);
                s8v aq[4];
                #pragma unroll
                for (int e = 0; e < 4; ++e) aq[e] = *(const s8v*)(asrc + e * 512 + L * 8);
                #pragma unroll
                for (int g = 0; g < 4; ++g) {
                    const int j = kq * 4 + g;          // group 4+j, acc gate = g
                    if ((j & 1) == 0) {
                        if (j == 0) { WAIT4(bufA, 7); } // g4 (younger: 3 inputs + g5)
                        else        { WAIT4(bufA, 4); }
                        #pragma unroll
                        for (int e = 0; e < 4; ++e)
                            accP[g] = __builtin_amdgcn_mfma_f32_16x16x32_bf16(
                                aq[e], __builtin_bit_cast(s8v, bufA[e]), accP[g], 0, 0, 0);
                        ISSUE4(bufA, wb + ((4 + j + 2) % 20) * 2048);
                    } else {
                        WAIT4(bufB, 4);
                        #pragma unroll
                        for (int e = 0; e < 4; ++e)
                            accP[g] = __builtin_amdgcn_mfma_f32_16x16x32_bf16(
                                aq[e], __builtin_bit_cast(s8v, bufB[e]), accP[g], 0, 0, 0);
                        ISSUE4(bufB, wb + ((4 + j + 2) % 20) * 2048);
                    }
                }
            }
            // tie next-step inputs (they are older than the 8 outstanding loads)
            asm volatile("s_waitcnt vmcnt(8)" : "+v"(xvr), "+v"(mvr), "+v"(dvr));
            #pragma unroll
            for (int r = 0; r < 4; ++r) {
                float gi = accP[0][r] + gbv[0];
                float gf = accP[1][r] + gbv[1];
                float gg = accP[2][r] + gbv[2];
                float go = accP[3][r] + gbv[3];
                float ct = fsigm(gf) * cst[r] + fsigm(gi) * ftanh(gg);
                cst[r] = ct;
                hv[r] = fsigm(go) * ftanh(ct);
            }
            // stage t+1 (x32/m32/dA; gxm staged next P1 from regs)
            *(f2v*)(x32 + v * 132 + f2) = xvr;
            *(f2v*)(m32 + v * 132 + f2) = mvr;
            *(uint32_t*)(dA + aidx(f2, v)) = pack2(dvr[0], dvr[1]);
        }
        block_sync();  // S5 == next step's S1
    }
    // drain outstanding weight loads before s_endpgm (no dangling VMEM returns)
    asm volatile("s_waitcnt vmcnt(0) lgkmcnt(0)" ::: "memory");
}

// ---------------- finisher ----------------
__global__ void finisher(const float* __restrict__ part, const float* __restrict__ msum,
                         float* __restrict__ out2) {
    int t = threadIdx.x;
    float s1 = part[t], s2 = part[TT + t], s3 = part[2 * TT + t];
    float den = msum[t] + EPSL;
    float l12 = (s1 + s2) / den;
    float l3 = s3 / den;
    float xl = l12 + (float)(TT - t) * l3;
    float ml = l3;
    __shared__ float r1[4], r2[4];
    for (int off = 32; off; off >>= 1) {
        xl += __shfl_down(xl, off);
        ml += __shfl_down(ml, off);
    }
    if ((t & 63) == 0) { r1[t >> 6] = xl; r2[t >> 6] = ml; }
    __syncthreads();
    if (t == 0) {
        float X = r1[0] + r1[1] + r1[2] + r1[3];
        float M = r2[0] + r2[1] + r2[2] + r2[3];
        out2[0] = X / (float)(TT * 3);
        out2[1] = M / (float)TT;
    }
}

extern "C" void kernel_launch(void* const* d_in, const int* in_sizes, int n_in,
                              void* d_out, int out_size, void* d_ws, size_t ws_size,
                              hipStream_t stream) {
    const float* values = (const float*)d_in[0];
    const float* mask   = (const float*)d_in[1];
    const float* deltas = (const float*)d_in[2];
    const float* Wdh = (const float*)d_in[3];
    const float* bdh = (const float*)d_in[4];
    const float* Wdx = (const float*)d_in[5];
    const float* bdx = (const float*)d_in[6];
    const float* Wh  = (const float*)d_in[7];
    const float* bh  = (const float*)d_in[8];
    const float* Wf  = (const float*)d_in[9];
    const float* bf_ = (const float*)d_in[10];
    const float* Wc  = (const float*)d_in[11];
    const float* bc_ = (const float*)d_in[12];
    const float* Wih = (const float*)d_in[13];
    const float* Whh = (const float*)d_in[14];
    const float* bih = (const float*)d_in[15];
    const float* bhh = (const float*)d_in[16];

    float* out = (float*)d_out;
    uint16_t* wsu = (uint16_t*)d_ws;
    float* msum = (float*)((char*)d_ws + OFF_MSUM);
    float* part = (float*)((char*)d_ws + OFF_PART);

    prep_weights<<<2560, 256, 0, stream>>>(Wdh, Wh, Wf, Wc, Wih, Whh, wsu);
    msum_kernel<<<TT, 256, 0, stream>>>(mask, msum, part);
    rits_main<<<NB, 1024, 0, stream>>>(values, mask, deltas, bdh, Wdx, bdx,
                                       bh, bf_, bc_, bih, bhh, wsu, part, out);
    finisher<<<1, 256, 0, stream>>>(part, msum, out + (long)BB * TT * FF);
}